// Round 1
// baseline (280.247 us; speedup 1.0000x reference)
//
#include <hip/hip_runtime.h>
#include <stdint.h>

// ---------------------------------------------------------------------------
// RoPEAttention: x[2,2048,1024] --Wqkv--> q,k,v --RoPE(q,k)--> softmax(qk^T/8)v
//                --Wout,bout--> out[2,2048,1024]  (all fp32 I/O, bf16 MFMA core)
//
// ws layout (42.5 MB):
//   [0,8M)      xb   bf16 [4096][1024]   (aliased by Obuf after attention)
//   [8M,14M)    wqkvb bf16 [3072][1024]
//   [14M,16M)   woutb bf16 [1024][1024]
//   ...         cosT/sinT fp32 [2048][32]
//   ...         Qbuf/Kbuf bf16 [32][2048][64], Vt bf16 [32][64][2048]
// ---------------------------------------------------------------------------

#define DI __device__ __forceinline__

typedef __attribute__((ext_vector_type(8))) __bf16 bf16x8;
typedef __attribute__((ext_vector_type(8))) short short8;
typedef __attribute__((ext_vector_type(4))) float f32x4;

DI unsigned short f2bf(float f) {
    union { float f; uint32_t u; } v; v.f = f;
    uint32_t r = v.u + 0x7FFFu + ((v.u >> 16) & 1u);   // RNE
    return (unsigned short)(r >> 16);
}

DI bf16x8 asb(short8 s) { union { short8 s; bf16x8 b; } u; u.s = s; return u.b; }

DI void gload16(const void* g, void* l) {
    __builtin_amdgcn_global_load_lds(
        (const __attribute__((address_space(1))) void*)g,
        (__attribute__((address_space(3))) void*)l, 16, 0, 0);
}

// --------------------------- cast fp32 -> bf16 -----------------------------
__global__ __launch_bounds__(256) void castk(const float* __restrict__ in,
                                             unsigned short* __restrict__ out, int n4) {
    int i = blockIdx.x * 256 + threadIdx.x;
    if (i < n4) {
        float4 v = ((const float4*)in)[i];
        union { unsigned short u[4]; uint2 q; } p;
        p.u[0] = f2bf(v.x); p.u[1] = f2bf(v.y); p.u[2] = f2bf(v.z); p.u[3] = f2bf(v.w);
        ((uint2*)out)[i] = p.q;
    }
}

// --------------------------- RoPE table [2048][32] -------------------------
__global__ __launch_bounds__(256) void ropek(float* __restrict__ cosT,
                                             float* __restrict__ sinT) {
    int i = blockIdx.x * 256 + threadIdx.x;     // 65536 total
    int n = i >> 5, d = i & 31;
    float inv = powf(10000.0f, -(float)(2 * d) * (1.0f / 64.0f));
    float a = (float)n * inv;
    float s, c;
    sincosf(a, &s, &c);
    cosT[i] = c; sinT[i] = s;
}

// ---------------------- GEMM C = A * Bt^T  (bf16 MFMA) ---------------------
// 128x128 tile, 4 waves (2x2), BK=32, 16x16x32 bf16 MFMA.
// MODE 0: qkv epilogue (RoPE on q,k; scatter to Qbuf/Kbuf[bh][n][64], Vt[bh][64][n])
// MODE 1: out epilogue (+bias, fp32 store)
template <int MODE>
__global__ __launch_bounds__(256) void gemm_bt(
    const unsigned short* __restrict__ A, const unsigned short* __restrict__ Bt,
    int M, int N, int K,
    unsigned short* __restrict__ Qbuf, unsigned short* __restrict__ Kbuf,
    unsigned short* __restrict__ Vt,
    const float* __restrict__ cosT, const float* __restrict__ sinT,
    float* __restrict__ Cout, const float* __restrict__ bias) {
    __shared__ unsigned short As[128 * 32];
    __shared__ unsigned short Bs[128 * 32];
    const int tid = threadIdx.x;
    const int wave = tid >> 6, lane = tid & 63, g = lane >> 4, li = lane & 15;
    const int wr = wave >> 1, wc = wave & 1;
    const int m0 = blockIdx.y * 128, n0 = blockIdx.x * 128;

    f32x4 acc[4][4] = {};
    const int nK = K >> 5;
    for (int kk = 0; kk < nK; ++kk) {
        {   // stage A,B tiles: 512 chunks of 16B each; LDS dest wave-uniform + lane*16
            int cb0 = wave * 64;
            int c0 = cb0 + lane;
            int r0 = c0 >> 2, k0 = (c0 & 3) * 8;
            gload16(A  + (size_t)(m0 + r0) * K + kk * 32 + k0, &As[cb0 * 8]);
            gload16(Bt + (size_t)(n0 + r0) * K + kk * 32 + k0, &Bs[cb0 * 8]);
            int cb1 = wave * 64 + 256;
            int c1 = cb1 + lane;
            int r1 = c1 >> 2, k1 = (c1 & 3) * 8;
            gload16(A  + (size_t)(m0 + r1) * K + kk * 32 + k1, &As[cb1 * 8]);
            gload16(Bt + (size_t)(n0 + r1) * K + kk * 32 + k1, &Bs[cb1 * 8]);
        }
        __syncthreads();
        short8 af[4], bf[4];
#pragma unroll
        for (int mi = 0; mi < 4; ++mi)
            af[mi] = *(const short8*)&As[(wr * 64 + mi * 16 + li) * 32 + g * 8];
#pragma unroll
        for (int ni = 0; ni < 4; ++ni)
            bf[ni] = *(const short8*)&Bs[(wc * 64 + ni * 16 + li) * 32 + g * 8];
#pragma unroll
        for (int mi = 0; mi < 4; ++mi)
#pragma unroll
            for (int ni = 0; ni < 4; ++ni)
                acc[mi][ni] = __builtin_amdgcn_mfma_f32_16x16x32_bf16(
                    asb(af[mi]), asb(bf[ni]), acc[mi][ni], 0, 0, 0);
        __syncthreads();
    }

    if (MODE == 1) {
#pragma unroll
        for (int mi = 0; mi < 4; ++mi) {
            int row = m0 + wr * 64 + mi * 16 + 4 * g;
#pragma unroll
            for (int ni = 0; ni < 4; ++ni) {
                int col = n0 + wc * 64 + ni * 16 + li;
                float b = bias[col];
#pragma unroll
                for (int r = 0; r < 4; ++r)
                    Cout[(size_t)(row + r) * N + col] = acc[mi][ni][r] + b;
            }
        }
    } else {
        // f = n0 + wc*64 + ni*16 + li ; three = f/1024, h = (f%1024)/64, d = f%64
        // wave's 64-col block is 64-aligned -> three,h uniform; d = ni*16+li
        const int fb = n0 + wc * 64;
        const int three = fb >> 10;
        const int h = (fb & 1023) >> 6;
#pragma unroll
        for (int mi = 0; mi < 4; ++mi) {
#pragma unroll
            for (int r = 0; r < 4; ++r) {
                int m = m0 + wr * 64 + mi * 16 + 4 * g + r;
                int b = m >> 11, n = m & 2047;
                float v0 = acc[mi][0][r], v1 = acc[mi][1][r];
                float v2 = acc[mi][2][r], v3 = acc[mi][3][r];
                size_t bh = (size_t)(b * 16 + h);
                if (three < 2) {
                    // RoPE: pairs (d, d+32); d = ni*16+li -> (ni, ni+2) in-lane
                    float c0 = cosT[n * 32 + li],      s0 = sinT[n * 32 + li];
                    float c1 = cosT[n * 32 + 16 + li], s1 = sinT[n * 32 + 16 + li];
                    float o0 = v0 * c0 - v2 * s0;
                    float o2 = v2 * c0 + v0 * s0;
                    float o1 = v1 * c1 - v3 * s1;
                    float o3 = v3 * c1 + v1 * s1;
                    unsigned short* dst = (three == 0 ? Qbuf : Kbuf) + (bh * 2048 + n) * 64;
                    dst[li] = f2bf(o0); dst[16 + li] = f2bf(o1);
                    dst[32 + li] = f2bf(o2); dst[48 + li] = f2bf(o3);
                } else {
                    unsigned short* dst = Vt + bh * 64 * 2048 + n;
                    dst[(size_t)(li) * 2048]      = f2bf(v0);
                    dst[(size_t)(16 + li) * 2048] = f2bf(v1);
                    dst[(size_t)(32 + li) * 2048] = f2bf(v2);
                    dst[(size_t)(48 + li) * 2048] = f2bf(v3);
                }
            }
        }
    }
}

// ------------------------------ attention ---------------------------------
// Per block: one (b,h), 64 q-rows; 4 waves x 16 q-rows each. K-tiles of 64.
// LDS row stride 88 ushorts (176B = 11*16B): aligned b128 + only 2-way bank alias.
#define KVS 88
__global__ __launch_bounds__(256) void attnk(
    const unsigned short* __restrict__ Qb, const unsigned short* __restrict__ Kb,
    const unsigned short* __restrict__ Vt, unsigned short* __restrict__ Obuf) {
    __shared__ unsigned short Ks[64 * KVS];          // [key][d]
    __shared__ unsigned short Vs[64 * KVS];          // [d][key]  (V^T tile)
    __shared__ unsigned short Ps[4][16 * KVS];       // per-wave P [q][key]
    const int tid = threadIdx.x, wave = tid >> 6, lane = tid & 63;
    const int g = lane >> 4, li = lane & 15;
    const int bh = blockIdx.y, qt = blockIdx.x;

    // Q fragments straight from global: A-frag = Q[row=li][d=g*8+j (+32)]
    const int qrow = qt * 64 + wave * 16 + li;
    const unsigned short* qp = Qb + ((size_t)bh * 2048 + qrow) * 64 + g * 8;
    short8 qf0 = *(const short8*)qp;
    short8 qf1 = *(const short8*)(qp + 32);

    f32x4 oacc[4] = {};
    float m_r[4], l_r[4];
#pragma unroll
    for (int r = 0; r < 4; ++r) { m_r[r] = -1e30f; l_r[r] = 0.f; }

    const int srow = lane;        // staging: row = lane, chunk = wave (+4)
    const int sc = wave;
    for (int kt = 0; kt < 32; ++kt) {
        const unsigned short* kg = Kb + ((size_t)bh * 2048 + kt * 64 + srow) * 64;
        const unsigned short* vg = Vt + ((size_t)bh * 64 + srow) * 2048 + kt * 64;
        *(short8*)&Ks[srow * KVS + sc * 8]       = *(const short8*)(kg + sc * 8);
        *(short8*)&Ks[srow * KVS + (sc + 4) * 8] = *(const short8*)(kg + (sc + 4) * 8);
        *(short8*)&Vs[srow * KVS + sc * 8]       = *(const short8*)(vg + sc * 8);
        *(short8*)&Vs[srow * KVS + (sc + 4) * 8] = *(const short8*)(vg + (sc + 4) * 8);
        __syncthreads();

        // S = Q K^T : D-layout col=key=li(+16*ct), row=q=4g+r
        f32x4 s[4] = {};
#pragma unroll
        for (int ct = 0; ct < 4; ++ct) {
            short8 kf0 = *(const short8*)&Ks[(ct * 16 + li) * KVS + g * 8];
            short8 kf1 = *(const short8*)&Ks[(ct * 16 + li) * KVS + 32 + g * 8];
            s[ct] = __builtin_amdgcn_mfma_f32_16x16x32_bf16(asb(qf0), asb(kf0), s[ct], 0, 0, 0);
            s[ct] = __builtin_amdgcn_mfma_f32_16x16x32_bf16(asb(qf1), asb(kf1), s[ct], 0, 0, 0);
        }
#pragma unroll
        for (int ct = 0; ct < 4; ++ct)
#pragma unroll
            for (int r = 0; r < 4; ++r) s[ct][r] *= 0.125f;

        // online softmax (fp32); row r lives in lanes with same g across li
        float alpha[4];
#pragma unroll
        for (int r = 0; r < 4; ++r) {
            float mx = fmaxf(fmaxf(s[0][r], s[1][r]), fmaxf(s[2][r], s[3][r]));
            mx = fmaxf(mx, __shfl_xor(mx, 1));
            mx = fmaxf(mx, __shfl_xor(mx, 2));
            mx = fmaxf(mx, __shfl_xor(mx, 4));
            mx = fmaxf(mx, __shfl_xor(mx, 8));
            float mnew = fmaxf(m_r[r], mx);
            alpha[r] = __expf(m_r[r] - mnew);
            m_r[r] = mnew;
            float ps = 0.f;
#pragma unroll
            for (int ct = 0; ct < 4; ++ct) {
                float p = __expf(s[ct][r] - mnew);
                s[ct][r] = p; ps += p;
            }
            ps += __shfl_xor(ps, 1); ps += __shfl_xor(ps, 2);
            ps += __shfl_xor(ps, 4); ps += __shfl_xor(ps, 8);
            l_r[r] = l_r[r] * alpha[r] + ps;
        }
#pragma unroll
        for (int dt = 0; dt < 4; ++dt)
#pragma unroll
            for (int r = 0; r < 4; ++r) oacc[dt][r] *= alpha[r];

        // P: D-layout -> LDS -> A-layout (wave-private, no barrier needed)
#pragma unroll
        for (int ct = 0; ct < 4; ++ct)
#pragma unroll
            for (int r = 0; r < 4; ++r)
                Ps[wave][(4 * g + r) * KVS + ct * 16 + li] = f2bf(s[ct][r]);

#pragma unroll
        for (int ks = 0; ks < 2; ++ks) {
            short8 pf = *(const short8*)&Ps[wave][li * KVS + ks * 32 + g * 8];
#pragma unroll
            for (int dt = 0; dt < 4; ++dt) {
                short8 vf = *(const short8*)&Vs[(dt * 16 + li) * KVS + ks * 32 + g * 8];
                oacc[dt] = __builtin_amdgcn_mfma_f32_16x16x32_bf16(asb(pf), asb(vf), oacc[dt], 0, 0, 0);
            }
        }
        __syncthreads();
    }

    const int b = bh >> 4, hh = bh & 15;
#pragma unroll
    for (int dt = 0; dt < 4; ++dt)
#pragma unroll
        for (int r = 0; r < 4; ++r) {
            int n = qt * 64 + wave * 16 + 4 * g + r;
            float ov = oacc[dt][r] / l_r[r];
            Obuf[((size_t)(b * 2048 + n)) * 1024 + hh * 64 + dt * 16 + li] = f2bf(ov);
        }
}

// ------------------------------- launch ------------------------------------
extern "C" void kernel_launch(void* const* d_in, const int* in_sizes, int n_in,
                              void* d_out, int out_size, void* d_ws, size_t ws_size,
                              hipStream_t stream) {
    const float* x    = (const float*)d_in[0];
    const float* Wqkv = (const float*)d_in[1];
    const float* Wout = (const float*)d_in[2];
    const float* bout = (const float*)d_in[3];
    float* out = (float*)d_out;
    char* ws = (char*)d_ws;

    size_t off = 0;
    unsigned short* xb    = (unsigned short*)(ws + off);             // 8 MB
    unsigned short* Obuf  = xb;                                      // alias (xb dead after gemm0)
    off += (size_t)4096 * 1024 * 2;
    unsigned short* wqkvb = (unsigned short*)(ws + off); off += (size_t)3072 * 1024 * 2;
    unsigned short* woutb = (unsigned short*)(ws + off); off += (size_t)1024 * 1024 * 2;
    float* cosT = (float*)(ws + off); off += (size_t)2048 * 32 * 4;
    float* sinT = (float*)(ws + off); off += (size_t)2048 * 32 * 4;
    unsigned short* Qbuf = (unsigned short*)(ws + off); off += (size_t)32 * 2048 * 64 * 2;
    unsigned short* Kbuf = (unsigned short*)(ws + off); off += (size_t)32 * 2048 * 64 * 2;
    unsigned short* Vt   = (unsigned short*)(ws + off); off += (size_t)32 * 64 * 2048 * 2;

    castk<<<4096, 256, 0, stream>>>(x, xb, 1048576);
    castk<<<3072, 256, 0, stream>>>(Wqkv, wqkvb, 786432);
    castk<<<1024, 256, 0, stream>>>(Wout, woutb, 262144);
    ropek<<<256, 256, 0, stream>>>(cosT, sinT);

    gemm_bt<0><<<dim3(24, 32), 256, 0, stream>>>(
        xb, wqkvb, 4096, 3072, 1024, Qbuf, Kbuf, Vt, cosT, sinT, nullptr, nullptr);

    attnk<<<dim3(32, 32), 256, 0, stream>>>(Qbuf, Kbuf, Vt, Obuf);

    gemm_bt<1><<<dim3(8, 32), 256, 0, stream>>>(
        Obuf, woutb, 4096, 1024, 1024, nullptr, nullptr, nullptr, nullptr, nullptr,
        out, bout);
}

// Round 3
// 218.046 us; speedup vs baseline: 1.2853x; 1.2853x over previous
//
#include <hip/hip_runtime.h>
#include <stdint.h>

#define DI __device__ __forceinline__

typedef __attribute__((ext_vector_type(8))) __bf16 bf16x8;
typedef __attribute__((ext_vector_type(8))) short short8;
typedef __attribute__((ext_vector_type(4))) float f32x4;
typedef __attribute__((ext_vector_type(16))) float f32x16;

DI unsigned short f2bf(float f) {
    union { float f; uint32_t u; } v; v.f = f;
    uint32_t r = v.u + 0x7FFFu + ((v.u >> 16) & 1u);   // RNE
    return (unsigned short)(r >> 16);
}
DI uint32_t pk2(float a, float b) { return (uint32_t)f2bf(a) | ((uint32_t)f2bf(b) << 16); }
DI bf16x8 asb(short8 s) { union { short8 s; bf16x8 b; } u; u.s = s; return u.b; }
DI bf16x8 asb4(uint32_t a, uint32_t b, uint32_t c, uint32_t d) {
    union { uint32_t u[4]; bf16x8 b; } x; x.u[0] = a; x.u[1] = b; x.u[2] = c; x.u[3] = d; return x.b;
}
DI void gload16(const void* g, void* l) {
    __builtin_amdgcn_global_load_lds(
        (const __attribute__((address_space(1))) void*)g,
        (__attribute__((address_space(3))) void*)l, 16, 0, 0);
}
DI int swzc(int c) { return c ^ ((c >> 3) & 7); }   // XOR chunk swizzle within a row

// --------------------------- cast fp32 -> bf16 -----------------------------
__global__ __launch_bounds__(256) void castk(const float* __restrict__ in,
                                             unsigned short* __restrict__ out, int n4) {
    int i = blockIdx.x * 256 + threadIdx.x;
    if (i < n4) {
        float4 v = ((const float4*)in)[i];
        union { unsigned short u[4]; uint2 q; } p;
        p.u[0] = f2bf(v.x); p.u[1] = f2bf(v.y); p.u[2] = f2bf(v.z); p.u[3] = f2bf(v.w);
        ((uint2*)out)[i] = p.q;
    }
}

// --------------------------- RoPE table [2048][32] -------------------------
__global__ __launch_bounds__(256) void ropek(float* __restrict__ cosT,
                                             float* __restrict__ sinT) {
    int i = blockIdx.x * 256 + threadIdx.x;     // 65536 total
    int n = i >> 5, d = i & 31;
    float inv = powf(10000.0f, -(float)(2 * d) * (1.0f / 64.0f));
    float a = (float)n * inv;
    float s, c;
    sincosf(a, &s, &c);
    cosT[i] = c; sinT[i] = s;
}

// ---------------------- GEMM C = A * Bt^T  (bf16 MFMA) ---------------------
// Tile BM x 128, 4 waves (2x2), BK=32, 16x16x32 bf16 MFMA (m97 shape, R1-proven).
// MODE 0 (BM=128): qkv epilogue (RoPE; Q scaled 1/8; V transposed via LDS)
// MODE 1 (BM=64):  out epilogue (+bias, fp32 store)
template <int MODE, int BM>
__global__ __launch_bounds__(256) void gemm_bt(
    const unsigned short* __restrict__ A, const unsigned short* __restrict__ Bt,
    int M, int N, int K,
    unsigned short* __restrict__ Qbuf, unsigned short* __restrict__ Kbuf,
    unsigned short* __restrict__ Vt,
    const float* __restrict__ cosT, const float* __restrict__ sinT,
    float* __restrict__ Cout, const float* __restrict__ bias) {
    constexpr int WM = BM / 2;       // rows per wave
    constexpr int MI = WM / 16;      // A-frag count per wave
    __shared__ __align__(16) unsigned short As[BM * 32];
    __shared__ __align__(16) unsigned short Bs[128 * 32];
    const int tid = threadIdx.x;
    const int wave = tid >> 6, lane = tid & 63, g = lane >> 4, li = lane & 15;
    const int wr = wave >> 1, wc = wave & 1;
    const int m0 = blockIdx.y * BM, n0 = blockIdx.x * 128;

    f32x4 acc[MI][4] = {};
    const int nK = K >> 5;
    for (int kk = 0; kk < nK; ++kk) {
#pragma unroll
        for (int i = 0; i < BM / 64; ++i) {     // A tile: BM*4 chunks of 16B
            int cb = i * 256 + wave * 64;
            int c = cb + lane;
            int r = c >> 2, k0 = (c & 3) * 8;
            gload16(A + (size_t)(m0 + r) * K + kk * 32 + k0, &As[cb * 8]);
        }
#pragma unroll
        for (int i = 0; i < 2; ++i) {           // B tile: 512 chunks
            int cb = i * 256 + wave * 64;
            int c = cb + lane;
            int r = c >> 2, k0 = (c & 3) * 8;
            gload16(Bt + (size_t)(n0 + r) * K + kk * 32 + k0, &Bs[cb * 8]);
        }
        __syncthreads();
        short8 af[MI], bf[4];
#pragma unroll
        for (int mi = 0; mi < MI; ++mi)
            af[mi] = *(const short8*)&As[(wr * WM + mi * 16 + li) * 32 + g * 8];
#pragma unroll
        for (int ni = 0; ni < 4; ++ni)
            bf[ni] = *(const short8*)&Bs[(wc * 64 + ni * 16 + li) * 32 + g * 8];
#pragma unroll
        for (int mi = 0; mi < MI; ++mi)
#pragma unroll
            for (int ni = 0; ni < 4; ++ni)
                acc[mi][ni] = __builtin_amdgcn_mfma_f32_16x16x32_bf16(
                    asb(af[mi]), asb(bf[ni]), acc[mi][ni], 0, 0, 0);
        __syncthreads();
    }

    if (MODE == 1) {
#pragma unroll
        for (int mi = 0; mi < MI; ++mi) {
            int row = m0 + wr * WM + mi * 16 + 4 * g;
#pragma unroll
            for (int ni = 0; ni < 4; ++ni) {
                int col = n0 + wc * 64 + ni * 16 + li;
                float b = bias[col];
#pragma unroll
                for (int r = 0; r < 4; ++r)
                    Cout[(size_t)(row + r) * N + col] = acc[mi][ni][r] + b;
            }
        }
    } else {
        // three = fb/1024 is block-uniform (n0 mult of 128 -> n0,n0+64 same 1K block)
        const int fb = n0 + wc * 64;
        const int three = fb >> 10;
        const int hh = (fb & 1023) >> 6;
        const int bq = m0 >> 11;
        const int nb0 = m0 & 2047;
        const size_t bh = (size_t)(bq * 16 + hh);
        if (three < 2) {
            // Q/K with RoPE; Q additionally scaled by 1/8 (softmax scale fold)
#pragma unroll
            for (int mi = 0; mi < MI; ++mi) {
#pragma unroll
                for (int r = 0; r < 4; ++r) {
                    int n = nb0 + wr * WM + mi * 16 + 4 * g + r;
                    float v0 = acc[mi][0][r], v1 = acc[mi][1][r];
                    float v2 = acc[mi][2][r], v3 = acc[mi][3][r];
                    float c0 = cosT[n * 32 + li],      s0 = sinT[n * 32 + li];
                    float c1 = cosT[n * 32 + 16 + li], s1 = sinT[n * 32 + 16 + li];
                    float o0 = v0 * c0 - v2 * s0;
                    float o2 = v2 * c0 + v0 * s0;
                    float o1 = v1 * c1 - v3 * s1;
                    float o3 = v3 * c1 + v1 * s1;
                    if (three == 0) { o0 *= 0.125f; o1 *= 0.125f; o2 *= 0.125f; o3 *= 0.125f; }
                    unsigned short* dst = (three == 0 ? Qbuf : Kbuf) + (bh * 2048 + n) * 64;
                    dst[li] = f2bf(o0); dst[16 + li] = f2bf(o1);
                    dst[32 + li] = f2bf(o2); dst[48 + li] = f2bf(o3);
                }
            }
        } else {
            // V: per-wave transpose through LDS (reuse As), block-barriered
            unsigned short* vtw = As + wave * 1024;        // [64 d][16 n]
#pragma unroll
            for (int mi = 0; mi < MI; ++mi) {
                __syncthreads();               // prev-mi reads (and K-loop) fully done
#pragma unroll
                for (int ni = 0; ni < 4; ++ni)
#pragma unroll
                    for (int r = 0; r < 4; ++r)
                        vtw[(ni * 16 + li) * 16 + 4 * g + r] = f2bf(acc[mi][ni][r]);
                __syncthreads();               // transpose writes visible
                uint4 lo = *(const uint4*)&vtw[lane * 16];
                uint4 hi = *(const uint4*)&vtw[lane * 16 + 8];
                int nbase = nb0 + wr * WM + mi * 16;
                unsigned short* dst = Vt + (bh * 64 + lane) * 2048 + nbase;
                *(uint4*)dst = lo;
                *(uint4*)(dst + 8) = hi;
            }
        }
    }
}

// ------------------------------ attention ---------------------------------
// 32x32x16 MFMA, swapped QK^T (S^T = K*Q^T): each lane owns one q-row.
// Reg-staged K/V (global->VGPR->ds_write_b128, XOR-swizzled chunk), double-
// buffered LDS, ONE barrier per KV tile. Next-tile loads fly under compute.
#define THR 8.0f
__global__ __launch_bounds__(256) void attnk(
    const unsigned short* __restrict__ Qb, const unsigned short* __restrict__ Kb,
    const unsigned short* __restrict__ Vt, unsigned short* __restrict__ Obuf) {
    __shared__ __align__(16) unsigned short Ks[2][64 * 64];
    __shared__ __align__(16) unsigned short Vs[2][64 * 64];
    const int tid = threadIdx.x, wave = tid >> 6, lane = tid & 63;
    const int h = lane >> 5, li = lane & 31;

    // XCD-bijective swizzle: 512 blocks / 8 XCDs
    const int fid = blockIdx.y * 16 + blockIdx.x;
    const int logical = (fid & 7) * 64 + (fid >> 3);
    const int bh = logical >> 4, qt = logical & 15;
    const int q0 = qt * 128 + wave * 32;

    // Q B-frags: lane holds Q[q0+li][16c + 8h + j]  (pre-scaled by 1/8)
    bf16x8 qf[4];
    const unsigned short* qp = Qb + ((size_t)bh * 2048 + q0 + li) * 64;
#pragma unroll
    for (int c = 0; c < 4; ++c) qf[c] = asb(*(const short8*)(qp + c * 16 + h * 8));

    // staging geometry: chunk c in [0,512): row=c>>3 (key for K, d for V), cc=c&7
    const uint4* kg = (const uint4*)(Kb + (size_t)bh * 2048 * 64);   // K tile kt: chunks kt*512+[0,512)
    const uint4* vg = (const uint4*)Vt;
    const int r0 = tid >> 3, r1 = (tid + 256) >> 3, cc = tid & 7;
    const int sw0 = swzc(tid) * 8, sw1 = swzc(tid + 256) * 8;
    const size_t vrow0 = ((size_t)bh * 64 + r0) * 256 + cc;
    const size_t vrow1 = ((size_t)bh * 64 + r1) * 256 + cc;

    uint4 kr0 = kg[tid], kr1 = kg[256 + tid];
    uint4 vr0 = vg[vrow0], vr1 = vg[vrow1];

    f32x16 o0 = {}, o1 = {};
    float m_ = -1e30f, l_ = 0.f;

    for (int kt = 0; kt < 32; ++kt) {
        const int cur = kt & 1;
        // write staged tile kt into buffer cur
        *(uint4*)&Ks[cur][sw0] = kr0;
        *(uint4*)&Ks[cur][sw1] = kr1;
        *(uint4*)&Vs[cur][sw0] = vr0;
        *(uint4*)&Vs[cur][sw1] = vr1;
        if (kt < 31) {      // issue next-tile loads; land under compute
            int nt = kt + 1;
            kr0 = kg[nt * 512 + tid]; kr1 = kg[nt * 512 + 256 + tid];
            vr0 = vg[vrow0 + nt * 8]; vr1 = vg[vrow1 + nt * 8];
        }
        __syncthreads();    // single barrier: writes(kt) visible; reads(kt-1) long done

        // S^T = K Q^T : col=li=q, row=(r&3)+8*(r>>2)+4h = key
        f32x16 s0 = {}, s1 = {};
#pragma unroll
        for (int c = 0; c < 4; ++c) {
            int ch = 2 * c + h;
            bf16x8 k0 = asb(*(const short8*)&Ks[cur][li * 64 + ((ch ^ (li & 7)) * 8)]);
            bf16x8 k1 = asb(*(const short8*)&Ks[cur][(32 + li) * 64 + ((ch ^ (li & 7)) * 8)]);
            s0 = __builtin_amdgcn_mfma_f32_32x32x16_bf16(k0, qf[c], s0, 0, 0, 0);
            s1 = __builtin_amdgcn_mfma_f32_32x32x16_bf16(k1, qf[c], s1, 0, 0, 0);
        }

        // online softmax, one q-row per lane (row li), reduce over h only
        float pmax = fmaxf(s0[0], s1[0]);
#pragma unroll
        for (int r = 1; r < 16; ++r) pmax = fmaxf(pmax, fmaxf(s0[r], s1[r]));
        pmax = fmaxf(pmax, __shfl_xor(pmax, 32));

        if (!__all(pmax <= m_ + THR)) {          // defer-max rescale
            float mn = fmaxf(m_, pmax);
            float al = __expf(m_ - mn);
            m_ = mn; l_ *= al;
#pragma unroll
            for (int r = 0; r < 16; ++r) {
                float ar = __shfl(al, (r & 3) + 8 * (r >> 2) + 4 * h);
                o0[r] *= ar; o1[r] *= ar;
            }
        }
        float sum = 0.f;
#pragma unroll
        for (int r = 0; r < 16; ++r) {
            float p0 = __expf(s0[r] - m_); s0[r] = p0; sum += p0;
            float p1 = __expf(s1[r] - m_); s1[r] = p1; sum += p1;
        }
        sum += __shfl_xor(sum, 32);
        l_ += sum;

        // pack P to bf16 words
        uint32_t w0[8], w1[8];
#pragma unroll
        for (int m = 0; m < 8; ++m) {
            w0[m] = pk2(s0[2 * m], s0[2 * m + 1]);
            w1[m] = pk2(s1[2 * m], s1[2 * m + 1]);
        }

        // PV: O += P V ; A-frag built in-register via xor-32 exchange
#pragma unroll
        for (int ks = 0; ks < 4; ++ks) {
            const uint32_t* wk = (ks < 2) ? w0 : w1;
            int sub = (ks & 1) * 4;
            uint32_t a0 = wk[sub], a1 = wk[sub + 1], a2 = wk[sub + 2], a3 = wk[sub + 3];
            uint32_t x0 = __shfl_xor(a0, 32), x1 = __shfl_xor(a1, 32);
            uint32_t x2 = __shfl_xor(a2, 32), x3 = __shfl_xor(a3, 32);
            uint32_t d0 = h ? x2 : a0;
            uint32_t d1 = h ? x3 : a1;
            uint32_t d2 = h ? a2 : x0;
            uint32_t d3 = h ? a3 : x1;
            bf16x8 pf = asb4(d0, d1, d2, d3);
            int ch = 2 * ks + h;
            bf16x8 vf0 = asb(*(const short8*)&Vs[cur][li * 64 + ((ch ^ (li & 7)) * 8)]);
            bf16x8 vf1 = asb(*(const short8*)&Vs[cur][(32 + li) * 64 + ((ch ^ (li & 7)) * 8)]);
            o0 = __builtin_amdgcn_mfma_f32_32x32x16_bf16(pf, vf0, o0, 0, 0, 0);
            o1 = __builtin_amdgcn_mfma_f32_32x32x16_bf16(pf, vf1, o1, 0, 0, 0);
        }
        // no trailing barrier: next iteration writes the OTHER buffer; the
        // buffer written in kt+2 is protected by barrier(kt+1)'s lgkm drain.
    }

    // epilogue: normalize rows and store bf16
    float linv = 1.0f / l_;
    const int b = bh >> 4, hh = bh & 15;
#pragma unroll
    for (int r = 0; r < 16; ++r) {
        int qrow = (r & 3) + 8 * (r >> 2) + 4 * h;
        float lr = __shfl(linv, qrow);
        int n = q0 + qrow;
        unsigned short* dst = Obuf + ((size_t)(b * 2048 + n)) * 1024 + hh * 64 + li;
        dst[0]  = f2bf(o0[r] * lr);
        dst[32] = f2bf(o1[r] * lr);
    }
}

// ------------------------------- launch ------------------------------------
extern "C" void kernel_launch(void* const* d_in, const int* in_sizes, int n_in,
                              void* d_out, int out_size, void* d_ws, size_t ws_size,
                              hipStream_t stream) {
    const float* x    = (const float*)d_in[0];
    const float* Wqkv = (const float*)d_in[1];
    const float* Wout = (const float*)d_in[2];
    const float* bout = (const float*)d_in[3];
    float* out = (float*)d_out;
    char* ws = (char*)d_ws;

    size_t off = 0;
    unsigned short* xb    = (unsigned short*)(ws + off);
    unsigned short* Obuf  = xb;                                      // alias
    off += (size_t)4096 * 1024 * 2;
    unsigned short* wqkvb = (unsigned short*)(ws + off); off += (size_t)3072 * 1024 * 2;
    unsigned short* woutb = (unsigned short*)(ws + off); off += (size_t)1024 * 1024 * 2;
    float* cosT = (float*)(ws + off); off += (size_t)2048 * 32 * 4;
    float* sinT = (float*)(ws + off); off += (size_t)2048 * 32 * 4;
    unsigned short* Qbuf = (unsigned short*)(ws + off); off += (size_t)32 * 2048 * 64 * 2;
    unsigned short* Kbuf = (unsigned short*)(ws + off); off += (size_t)32 * 2048 * 64 * 2;
    unsigned short* Vt   = (unsigned short*)(ws + off); off += (size_t)32 * 64 * 2048 * 2;

    castk<<<4096, 256, 0, stream>>>(x, xb, 1048576);
    castk<<<3072, 256, 0, stream>>>(Wqkv, wqkvb, 786432);
    castk<<<1024, 256, 0, stream>>>(Wout, woutb, 262144);
    ropek<<<256, 256, 0, stream>>>(cosT, sinT);

    gemm_bt<0, 128><<<dim3(24, 32), 256, 0, stream>>>(
        xb, wqkvb, 4096, 3072, 1024, Qbuf, Kbuf, Vt, cosT, sinT, nullptr, nullptr);

    attnk<<<dim3(16, 32), 256, 0, stream>>>(Qbuf, Kbuf, Vt, Obuf);

    gemm_bt<1, 64><<<dim3(8, 64), 256, 0, stream>>>(
        Obuf, woutb, 4096, 1024, 1024, nullptr, nullptr, nullptr, nullptr, nullptr,
        out, bout);
}

// Round 4
// 213.035 us; speedup vs baseline: 1.3155x; 1.0235x over previous
//
#include <hip/hip_runtime.h>
#include <stdint.h>

#define DI __device__ __forceinline__

typedef __attribute__((ext_vector_type(8))) __bf16 bf16x8;
typedef __attribute__((ext_vector_type(8))) short short8;
typedef __attribute__((ext_vector_type(4))) float f32x4;
typedef __attribute__((ext_vector_type(16))) float f32x16;

DI unsigned short f2bf(float f) {
    union { float f; uint32_t u; } v; v.f = f;
    uint32_t r = v.u + 0x7FFFu + ((v.u >> 16) & 1u);   // RNE
    return (unsigned short)(r >> 16);
}
DI uint32_t pk2(float a, float b) {        // {lo=bf16(a), hi=bf16(b)} in 1 instr
    uint32_t r;
    asm("v_cvt_pk_bf16_f32 %0, %1, %2" : "=v"(r) : "v"(a), "v"(b));
    return r;
}
DI bf16x8 asb(short8 s) { union { short8 s; bf16x8 b; } u; u.s = s; return u.b; }
DI bf16x8 asb4(uint32_t a, uint32_t b, uint32_t c, uint32_t d) {
    union { uint32_t u[4]; bf16x8 b; } x; x.u[0] = a; x.u[1] = b; x.u[2] = c; x.u[3] = d; return x.b;
}
DI void gload16(const void* g, void* l) {
    __builtin_amdgcn_global_load_lds(
        (const __attribute__((address_space(1))) void*)g,
        (__attribute__((address_space(3))) void*)l, 16, 0, 0);
}
DI int swzc(int c) { return c ^ ((c >> 3) & 7); }   // XOR chunk swizzle within a row

// ------------- fused prep: cast x/Wqkv/Wout to bf16 + RoPE table -----------
__global__ __launch_bounds__(256) void prepk(
    const float* __restrict__ x, const float* __restrict__ Wqkv,
    const float* __restrict__ Wout,
    unsigned short* __restrict__ xb, unsigned short* __restrict__ wqkvb,
    unsigned short* __restrict__ woutb,
    float* __restrict__ cosT, float* __restrict__ sinT) {
    const int bid = blockIdx.x, tid = threadIdx.x;
    if (bid < 8192) {
        const float* in; unsigned short* out; int i;
        if (bid < 4096)      { in = x;    out = xb;    i = bid * 256 + tid; }
        else if (bid < 7168) { in = Wqkv; out = wqkvb; i = (bid - 4096) * 256 + tid; }
        else                 { in = Wout; out = woutb; i = (bid - 7168) * 256 + tid; }
        float4 v = ((const float4*)in)[i];
        union { unsigned short u[4]; uint2 q; } p;
        p.u[0] = f2bf(v.x); p.u[1] = f2bf(v.y); p.u[2] = f2bf(v.z); p.u[3] = f2bf(v.w);
        ((uint2*)out)[i] = p.q;
    } else {
        int i = (bid - 8192) * 256 + tid;       // 65536 total
        int n = i >> 5, d = i & 31;
        float inv = powf(10000.0f, -(float)(2 * d) * (1.0f / 64.0f));
        float a = (float)n * inv;
        float s, c;
        sincosf(a, &s, &c);
        cosT[i] = c; sinT[i] = s;
    }
}

// ---------------------- GEMM C = A * Bt^T  (bf16 MFMA) ---------------------
// Tile BM x 128, 4 waves (2x2), BK=32, 16x16x32 bf16 MFMA (m97 shape, R1-proven).
// MODE 0 (BM=128): qkv epilogue (RoPE; Q scaled by log2e/8; V transposed via
//                  LDS with key-permuted layout: slot s holds key swap23(s))
// MODE 1 (BM=64):  out epilogue (+bias, fp32 store)
template <int MODE, int BM>
__global__ __launch_bounds__(256) void gemm_bt(
    const unsigned short* __restrict__ A, const unsigned short* __restrict__ Bt,
    int M, int N, int K,
    unsigned short* __restrict__ Qbuf, unsigned short* __restrict__ Kbuf,
    unsigned short* __restrict__ Vt,
    const float* __restrict__ cosT, const float* __restrict__ sinT,
    float* __restrict__ Cout, const float* __restrict__ bias) {
    constexpr int WM = BM / 2;       // rows per wave
    constexpr int MI = WM / 16;      // A-frag count per wave
    __shared__ __align__(16) unsigned short As[BM * 32];
    __shared__ __align__(16) unsigned short Bs[128 * 32];
    const int tid = threadIdx.x;
    const int wave = tid >> 6, lane = tid & 63, g = lane >> 4, li = lane & 15;
    const int wr = wave >> 1, wc = wave & 1;
    const int m0 = blockIdx.y * BM, n0 = blockIdx.x * 128;

    f32x4 acc[MI][4] = {};
    const int nK = K >> 5;
    for (int kk = 0; kk < nK; ++kk) {
#pragma unroll
        for (int i = 0; i < BM / 64; ++i) {     // A tile: BM*4 chunks of 16B
            int cb = i * 256 + wave * 64;
            int c = cb + lane;
            int r = c >> 2, k0 = (c & 3) * 8;
            gload16(A + (size_t)(m0 + r) * K + kk * 32 + k0, &As[cb * 8]);
        }
#pragma unroll
        for (int i = 0; i < 2; ++i) {           // B tile: 512 chunks
            int cb = i * 256 + wave * 64;
            int c = cb + lane;
            int r = c >> 2, k0 = (c & 3) * 8;
            gload16(Bt + (size_t)(n0 + r) * K + kk * 32 + k0, &Bs[cb * 8]);
        }
        __syncthreads();
        short8 af[MI], bf[4];
#pragma unroll
        for (int mi = 0; mi < MI; ++mi)
            af[mi] = *(const short8*)&As[(wr * WM + mi * 16 + li) * 32 + g * 8];
#pragma unroll
        for (int ni = 0; ni < 4; ++ni)
            bf[ni] = *(const short8*)&Bs[(wc * 64 + ni * 16 + li) * 32 + g * 8];
#pragma unroll
        for (int mi = 0; mi < MI; ++mi)
#pragma unroll
            for (int ni = 0; ni < 4; ++ni)
                acc[mi][ni] = __builtin_amdgcn_mfma_f32_16x16x32_bf16(
                    asb(af[mi]), asb(bf[ni]), acc[mi][ni], 0, 0, 0);
        __syncthreads();
    }

    if (MODE == 1) {
#pragma unroll
        for (int mi = 0; mi < MI; ++mi) {
            int row = m0 + wr * WM + mi * 16 + 4 * g;
#pragma unroll
            for (int ni = 0; ni < 4; ++ni) {
                int col = n0 + wc * 64 + ni * 16 + li;
                float b = bias[col];
#pragma unroll
                for (int r = 0; r < 4; ++r)
                    Cout[(size_t)(row + r) * N + col] = acc[mi][ni][r] + b;
            }
        }
    } else {
        // three = fb/1024 is block-uniform; hh differs per wave-column
        const int fb = n0 + wc * 64;
        const int three = fb >> 10;
        const int hh = (fb & 1023) >> 6;
        const int bq = m0 >> 11;
        const int nb0 = m0 & 2047;
        const size_t bh = (size_t)(bq * 16 + hh);
        if (three < 2) {
            // Q/K with RoPE; Q scaled by log2e/8 (base-2 softmax fold)
#pragma unroll
            for (int mi = 0; mi < MI; ++mi) {
#pragma unroll
                for (int r = 0; r < 4; ++r) {
                    int n = nb0 + wr * WM + mi * 16 + 4 * g + r;
                    float v0 = acc[mi][0][r], v1 = acc[mi][1][r];
                    float v2 = acc[mi][2][r], v3 = acc[mi][3][r];
                    float c0 = cosT[n * 32 + li],      s0 = sinT[n * 32 + li];
                    float c1 = cosT[n * 32 + 16 + li], s1 = sinT[n * 32 + 16 + li];
                    float o0 = v0 * c0 - v2 * s0;
                    float o2 = v2 * c0 + v0 * s0;
                    float o1 = v1 * c1 - v3 * s1;
                    float o3 = v3 * c1 + v1 * s1;
                    if (three == 0) {
                        const float qs = 0.18033688f;  // 0.125 * log2(e)
                        o0 *= qs; o1 *= qs; o2 *= qs; o3 *= qs;
                    }
                    unsigned short* dst = (three == 0 ? Qbuf : Kbuf) + (bh * 2048 + n) * 64;
                    dst[li] = f2bf(o0); dst[16 + li] = f2bf(o1);
                    dst[32 + li] = f2bf(o2); dst[48 + li] = f2bf(o3);
                }
            }
        } else {
            // V: per-wave transpose via LDS (reuse As), with key-permutation
            // swap23 within each 16-token group (PV sigma-layout, see attnk)
            unsigned short* vtw = As + wave * 1024;        // [64 d][16 slots]
            const int gsw = ((g & 1) << 1) | (g >> 1);     // swap 2-bit halves
#pragma unroll
            for (int mi = 0; mi < MI; ++mi) {
                __syncthreads();               // prev-mi reads fully done
#pragma unroll
                for (int ni = 0; ni < 4; ++ni)
#pragma unroll
                    for (int r = 0; r < 4; ++r)
                        vtw[(ni * 16 + li) * 16 + 4 * gsw + r] = f2bf(acc[mi][ni][r]);
                __syncthreads();               // transpose writes visible
                uint4 lo = *(const uint4*)&vtw[lane * 16];
                uint4 hi = *(const uint4*)&vtw[lane * 16 + 8];
                int nbase = nb0 + wr * WM + mi * 16;
                unsigned short* dst = Vt + (bh * 64 + lane) * 2048 + nbase;
                *(uint4*)dst = lo;
                *(uint4*)(dst + 8) = hi;
            }
        }
    }
}

// ------------------------------ attention ---------------------------------
// 32x32x16 MFMA, swapped QK^T (S^T = K*Q^T): each lane owns one q-row.
// Base-2 softmax (Q pre-scaled by log2e/8). V stored sigma-permuted so the
// PV A-frag is the lane's OWN packed P words (no cross-half exchange).
// Reg-staged K/V, double-buffered LDS, ONE barrier per KV tile.
#define THR2 11.0f     // defer-max threshold in log2 units (~8 nats)
__global__ __launch_bounds__(256) void attnk(
    const unsigned short* __restrict__ Qb, const unsigned short* __restrict__ Kb,
    const unsigned short* __restrict__ Vt, unsigned short* __restrict__ Obuf) {
    __shared__ __align__(16) unsigned short Ks[2][64 * 64];
    __shared__ __align__(16) unsigned short Vs[2][64 * 64];
    const int tid = threadIdx.x, wave = tid >> 6, lane = tid & 63;
    const int h = lane >> 5, li = lane & 31;

    // XCD-bijective swizzle: 512 blocks / 8 XCDs
    const int fid = blockIdx.y * 16 + blockIdx.x;
    const int logical = (fid & 7) * 64 + (fid >> 3);
    const int bh = logical >> 4, qt = logical & 15;
    const int q0 = qt * 128 + wave * 32;

    // Q B-frags: lane holds Q[q0+li][16c + 8h + j]  (pre-scaled by log2e/8)
    bf16x8 qf[4];
    const unsigned short* qp = Qb + ((size_t)bh * 2048 + q0 + li) * 64;
#pragma unroll
    for (int c = 0; c < 4; ++c) qf[c] = asb(*(const short8*)(qp + c * 16 + h * 8));

    // staging geometry: chunk c in [0,512): row=c>>3 (key for K, d for V), cc=c&7
    const uint4* kg = (const uint4*)(Kb + (size_t)bh * 2048 * 64);
    const uint4* vg = (const uint4*)Vt;
    const int r0 = tid >> 3, r1 = (tid + 256) >> 3, cc = tid & 7;
    const int sw0 = swzc(tid) * 8, sw1 = swzc(tid + 256) * 8;
    const size_t vrow0 = ((size_t)bh * 64 + r0) * 256 + cc;
    const size_t vrow1 = ((size_t)bh * 64 + r1) * 256 + cc;

    uint4 kr0 = kg[tid], kr1 = kg[256 + tid];
    uint4 vr0 = vg[vrow0], vr1 = vg[vrow1];

    f32x16 o0 = {}, o1 = {};
    float m_ = -1e30f, l_ = 0.f;

    for (int kt = 0; kt < 32; ++kt) {
        const int cur = kt & 1;
        *(uint4*)&Ks[cur][sw0] = kr0;
        *(uint4*)&Ks[cur][sw1] = kr1;
        *(uint4*)&Vs[cur][sw0] = vr0;
        *(uint4*)&Vs[cur][sw1] = vr1;
        if (kt < 31) {      // next-tile loads fly under compute
            int nt = kt + 1;
            kr0 = kg[nt * 512 + tid]; kr1 = kg[nt * 512 + 256 + tid];
            vr0 = vg[vrow0 + nt * 8]; vr1 = vg[vrow1 + nt * 8];
        }
        __syncthreads();    // writes(kt) visible; reads(kt-1) long done

        // S^T = K Q^T : col=li=q, row=(r&3)+8*(r>>2)+4h = key
        f32x16 s0 = {}, s1 = {};
#pragma unroll
        for (int c = 0; c < 4; ++c) {
            int ch = 2 * c + h;
            bf16x8 k0 = asb(*(const short8*)&Ks[cur][li * 64 + ((ch ^ (li & 7)) * 8)]);
            bf16x8 k1 = asb(*(const short8*)&Ks[cur][(32 + li) * 64 + ((ch ^ (li & 7)) * 8)]);
            s0 = __builtin_amdgcn_mfma_f32_32x32x16_bf16(k0, qf[c], s0, 0, 0, 0);
            s1 = __builtin_amdgcn_mfma_f32_32x32x16_bf16(k1, qf[c], s1, 0, 0, 0);
        }

        // online softmax in base 2, one q-row per lane (row li)
        float pmax = fmaxf(s0[0], s1[0]);
#pragma unroll
        for (int r = 1; r < 16; ++r) pmax = fmaxf(pmax, fmaxf(s0[r], s1[r]));
        pmax = fmaxf(pmax, __shfl_xor(pmax, 32));

        if (!__all(pmax <= m_ + THR2)) {          // defer-max rescale (rare)
            float mn = fmaxf(m_, pmax);
            float al = __builtin_exp2f(m_ - mn);
            m_ = mn; l_ *= al;
#pragma unroll
            for (int r = 0; r < 16; ++r) {
                float ar = __shfl(al, (r & 3) + 8 * (r >> 2) + 4 * h);
                o0[r] *= ar; o1[r] *= ar;
            }
        }
        float sum = 0.f;
#pragma unroll
        for (int r = 0; r < 16; ++r) {
            float p0 = __builtin_exp2f(s0[r] - m_); s0[r] = p0; sum += p0;
            float p1 = __builtin_exp2f(s1[r] - m_); s1[r] = p1; sum += p1;
        }
        sum += __shfl_xor(sum, 32);
        l_ += sum;

        // pack P to bf16 words (v_cvt_pk_bf16_f32)
        uint32_t w0[8], w1[8];
#pragma unroll
        for (int m = 0; m < 8; ++m) {
            w0[m] = pk2(s0[2 * m], s0[2 * m + 1]);
            w1[m] = pk2(s1[2 * m], s1[2 * m + 1]);
        }

        // PV: O += P V. sigma-permuted V makes lane's own words the A-frag.
#pragma unroll
        for (int ks = 0; ks < 4; ++ks) {
            const uint32_t* wk = (ks < 2) ? w0 : w1;
            const int sub = (ks & 1) * 4;
            bf16x8 pf = asb4(wk[sub], wk[sub + 1], wk[sub + 2], wk[sub + 3]);
            int ch = 2 * ks + h;
            bf16x8 vf0 = asb(*(const short8*)&Vs[cur][li * 64 + ((ch ^ (li & 7)) * 8)]);
            bf16x8 vf1 = asb(*(const short8*)&Vs[cur][(32 + li) * 64 + ((ch ^ (li & 7)) * 8)]);
            o0 = __builtin_amdgcn_mfma_f32_32x32x16_bf16(pf, vf0, o0, 0, 0, 0);
            o1 = __builtin_amdgcn_mfma_f32_32x32x16_bf16(pf, vf1, o1, 0, 0, 0);
        }
        // no trailing barrier (double-buffer WAR protected by next barrier)
    }

    // epilogue: normalize rows and store bf16
    float linv = 1.0f / l_;
    const int b = bh >> 4, hh = bh & 15;
#pragma unroll
    for (int r = 0; r < 16; ++r) {
        int qrow = (r & 3) + 8 * (r >> 2) + 4 * h;
        float lr = __shfl(linv, qrow);
        int n = q0 + qrow;
        unsigned short* dst = Obuf + ((size_t)(b * 2048 + n)) * 1024 + hh * 64 + li;
        dst[0]  = f2bf(o0[r] * lr);
        dst[32] = f2bf(o1[r] * lr);
    }
}

// ------------------------------- launch ------------------------------------
extern "C" void kernel_launch(void* const* d_in, const int* in_sizes, int n_in,
                              void* d_out, int out_size, void* d_ws, size_t ws_size,
                              hipStream_t stream) {
    const float* x    = (const float*)d_in[0];
    const float* Wqkv = (const float*)d_in[1];
    const float* Wout = (const float*)d_in[2];
    const float* bout = (const float*)d_in[3];
    float* out = (float*)d_out;
    char* ws = (char*)d_ws;

    size_t off = 0;
    unsigned short* xb    = (unsigned short*)(ws + off);
    unsigned short* Obuf  = xb;                                      // alias
    off += (size_t)4096 * 1024 * 2;
    unsigned short* wqkvb = (unsigned short*)(ws + off); off += (size_t)3072 * 1024 * 2;
    unsigned short* woutb = (unsigned short*)(ws + off); off += (size_t)1024 * 1024 * 2;
    float* cosT = (float*)(ws + off); off += (size_t)2048 * 32 * 4;
    float* sinT = (float*)(ws + off); off += (size_t)2048 * 32 * 4;
    unsigned short* Qbuf = (unsigned short*)(ws + off); off += (size_t)32 * 2048 * 64 * 2;
    unsigned short* Kbuf = (unsigned short*)(ws + off); off += (size_t)32 * 2048 * 64 * 2;
    unsigned short* Vt   = (unsigned short*)(ws + off); off += (size_t)32 * 64 * 2048 * 2;

    prepk<<<8448, 256, 0, stream>>>(x, Wqkv, Wout, xb, wqkvb, woutb, cosT, sinT);

    gemm_bt<0, 128><<<dim3(24, 32), 256, 0, stream>>>(
        xb, wqkvb, 4096, 3072, 1024, Qbuf, Kbuf, Vt, cosT, sinT, nullptr, nullptr);

    attnk<<<dim3(16, 32), 256, 0, stream>>>(Qbuf, Kbuf, Vt, Obuf);

    gemm_bt<1, 64><<<dim3(8, 64), 256, 0, stream>>>(
        Obuf, woutb, 4096, 1024, 1024, nullptr, nullptr, nullptr, nullptr, nullptr,
        out, bout);
}